// Round 1
// baseline (514.501 us; speedup 1.0000x reference)
//
#include <hip/hip_runtime.h>
#include <stdint.h>

#define NANCH 24564
#define NBATCH 32
#define NCLS 81
#define FEAT 93
#define NEGV -10000000000.0f
#define CONF_T 0.01f
#define IOU_T 0.45f
#define TOPK 200
#define CAP 1024
#define TARGET 768u
#define NBINS 1024
#define APB 64   // anchors per decode block
#define NF4 (APB * FEAT / 4)   // 1488 float4 per block

// ---------------------------------------------------------------- decode ----
// 256 threads, 64 anchors/block. Staging via global_load_lds (direct DMA,
// no VGPR round-trip). Then 4 lanes per anchor for the 81-class argmax,
// merged via __shfl_xor with the first-index tie rule (matches jnp.argmax).
__global__ __launch_bounds__(256) void decode_kernel(
    const float* __restrict__ yp, float4* __restrict__ boxes,
    float* __restrict__ scores, float* __restrict__ cls) {
#pragma clang fp contract(off)
  __shared__ float lds[APB * FEAT];   // 23808 B
  const float* src = yp + (size_t)blockIdx.x * (APB * FEAT);

  // global->LDS DMA: element i lands at LDS byte i*16; HW dest is
  // wave-uniform base (i&~63)*16 + lane*16, and i - (i&~63) == lane. exact.
  for (int i = threadIdx.x; i < NF4; i += 256) {
    int wb = i & ~63;   // wave-uniform
    __builtin_amdgcn_global_load_lds(
        (const __attribute__((address_space(1))) void*)(src + (size_t)i * 4),
        (__attribute__((address_space(3))) void*)(lds + wb * 4),
        16, 0, 0);
  }
  __syncthreads();   // compiler drains vmcnt before s_barrier

  const int L = threadIdx.x;
  const int a = L >> 2;          // anchor within block
  const int part = L & 3;
  const float* p = &lds[a * FEAT];

  int c0 = part * 21;
  int c1 = (part == 3) ? NCLS : c0 + 21;
  float best = -3.0e38f;
  int bi = c0;
  for (int c = c0; c < c1; ++c) {  // strict > keeps first index within part
    float v = p[c];
    if (v > best) { best = v; bi = c; }
  }
  // merge 4 parts: smaller index wins ties (parts are index-ordered)
  for (int off = 1; off < 4; off <<= 1) {
    float ov = __shfl_xor(best, off, 64);
    int   oi = __shfl_xor(bi, off, 64);
    if (ov > best || (ov == best && oi < bi)) { best = ov; bi = oi; }
  }

  if (part == 0) {
    float cx = p[81] * p[89] * p[87] + p[85];
    float cy = p[82] * p[90] * p[88] + p[86];
    float w  = expf(p[83] * p[91]) * p[87];
    float h  = expf(p[84] * p[92]) * p[88];
    float xmin = (cx - 0.5f * w) * 512.0f;
    float ymin = (cy - 0.5f * h) * 512.0f;
    float xmax = (cx + 0.5f * w) * 512.0f;
    float ymax = (cy + 0.5f * h) * 512.0f;
    int ga = blockIdx.x * APB + a;
    boxes[ga] = make_float4(xmin, ymin, xmax, ymax);
    cls[ga] = (float)bi;
    scores[ga] = (bi != 0 && best > CONF_T) ? best : NEGV;
  }
}

// Exact division-free IoU threshold test.
// RN_f32(inter/uni) > 0.45f  <=>  inter/uni > U  (U = midpoint(0.45f, succ);
// tie-to-even at U rounds to 0.45f whose mantissa is even -> strict).
// U has 25 mantissa bits, uni has 24 -> U*uni is EXACT in f64, so the f64
// compare is bit-equivalent to the reference's f32 divide-and-compare.
__device__ __forceinline__ bool iou_chk(float sx1, float sy1, float sx2, float sy2, float sarea,
                                        float bx1, float by1, float bx2, float by2, float barea) {
#pragma clang fp contract(off)
  float ix1 = fmaxf(sx1, bx1);
  float iy1 = fmaxf(sy1, by1);
  float ix2 = fminf(sx2, bx2);
  float iy2 = fminf(sy2, by2);
  float inter = fmaxf(ix2 - ix1, 0.0f) * fmaxf(iy2 - iy1, 0.0f);
  float uni = sarea + barea - inter;   // matches (area + areas) - inter
  const double UMID = 0.5 * ((double)0.45f + (double)__uint_as_float(0x3EE66667u));
  return (uni > 0.0f) && ((double)inter > UMID * (double)uni);
}

__device__ __forceinline__ unsigned long long maxu64(unsigned long long a, unsigned long long b) { return a > b ? a : b; }
__device__ __forceinline__ unsigned long long minu64(unsigned long long a, unsigned long long b) { return a < b ? a : b; }

// ------------------------------------------------------------------- nms ----
__global__ __launch_bounds__(1024) void nms_kernel(
    const float4* __restrict__ boxes, const float* __restrict__ scores,
    const float* __restrict__ cls, float* __restrict__ out) {
#pragma clang fp contract(off)
  __shared__ unsigned long long keys[CAP];   // 8 KB
  __shared__ float4 cbox[CAP];               // 16 KB
  __shared__ unsigned int hist[NBINS];       // 4 KB
  __shared__ float selb[TOPK * 5];
  __shared__ unsigned int sel_idx[TOPK];
  __shared__ float sel_score[TOPK];
  __shared__ unsigned int s_cnt;
  __shared__ int s_cutoff;
  __shared__ int s_nsel;

  const int b = blockIdx.x;
  const int tid = threadIdx.x;
  const size_t base = (size_t)b * NANCH;

  // phase 0: load 24 scores into registers (single global pass)
  float sreg[24];
#pragma unroll
  for (int j = 0; j < 24; ++j) {
    int i = tid + j * 1024;
    sreg[j] = (i < NANCH) ? scores[base + i] : NEGV;
  }

  // phase 1: histogram
  hist[tid] = 0u;
  if (tid == 0) { s_cnt = 0u; s_cutoff = 0; s_nsel = 0; }
  __syncthreads();
#pragma unroll
  for (int j = 0; j < 24; ++j) {
    float s = sreg[j];
    if (s >= 0.0f) {
      int bin = (int)(s * ((float)NBINS / 6.0f));
      bin = bin > (NBINS - 1) ? (NBINS - 1) : bin;
      atomicAdd(&hist[bin], 1u);
    }
  }
  __syncthreads();

  // phase 2: suffix-inclusive sums over 1024 bins, wave 0 only (shuffle scan)
  if (tid < 64) {
    int lane = tid;
    unsigned int h[16];
    unsigned int S = 0;
#pragma unroll
    for (int t = 0; t < 16; ++t) { h[t] = hist[lane * 16 + t]; S += h[t]; }
    unsigned int incl = S;
    for (int off = 1; off < 64; off <<= 1) {
      unsigned int o = __shfl_down(incl, off, 64);
      if (lane + off < 64) incl += o;
    }
    unsigned int acc = incl - S;   // exclusive suffix
#pragma unroll
    for (int t = 15; t >= 0; --t) { acc += h[t]; hist[lane * 16 + t] = acc; }
  }
  __syncthreads();
  {
    unsigned int sfx = hist[tid];
    unsigned int nxt = (tid < NBINS - 1) ? hist[tid + 1] : 0u;
    if (sfx >= TARGET && nxt < TARGET) s_cutoff = tid;   // unique writer
  }
  __syncthreads();
  float cutoffv = (float)s_cutoff * (6.0f / (float)NBINS);

  // phase 3: compact candidates >= cutoff from registers
#pragma unroll
  for (int j = 0; j < 24; ++j) {
    float s = sreg[j];
    if (s >= cutoffv) {   // NEGV always excluded
      unsigned int pos = atomicAdd(&s_cnt, 1u);
      if (pos < CAP) {
        unsigned int i = (unsigned int)(tid + j * 1024);
        keys[pos] = ((unsigned long long)__float_as_uint(s) << 32) |
                    (unsigned long long)(~i);
      }
    }
  }
  __syncthreads();
  int cnt = (int)(s_cnt > CAP ? CAP : s_cnt);

  // phase 4: hybrid bitonic sort (descending), 1 elem/thread.
  // j<64 steps: wave-local via 64-bit shfl_xor (no barrier). j>=64: LDS.
  unsigned long long v = (tid < cnt) ? keys[tid] : 0ull;
  for (int k = 2; k <= 64; k <<= 1) {
    for (int j = k >> 1; j >= 1; j >>= 1) {
      unsigned long long o = __shfl_xor((long long)v, j, 64);
      bool keepmax = (((tid & k) == 0) == ((tid & j) == 0));
      v = keepmax ? maxu64(v, o) : minu64(v, o);
    }
  }
  for (int k = 128; k <= CAP; k <<= 1) {
    for (int j = k >> 1; j >= 64; j >>= 1) {
      keys[tid] = v;
      __syncthreads();
      unsigned long long o = keys[tid ^ j];
      bool keepmax = (((tid & k) == 0) == ((tid & j) == 0));
      v = keepmax ? maxu64(v, o) : minu64(v, o);
      __syncthreads();
    }
    for (int j = 32; j >= 1; j >>= 1) {
      unsigned long long o = __shfl_xor((long long)v, j, 64);
      bool keepmax = (((tid & k) == 0) == ((tid & j) == 0));
      v = keepmax ? maxu64(v, o) : minu64(v, o);
    }
  }
  keys[tid] = v;
  __syncthreads();

  // phase 5: prefetch candidate boxes into LDS
  if (v != 0ull) {
    unsigned int idx = ~(unsigned int)(v & 0xFFFFFFFFull);
    cbox[tid] = boxes[base + idx];
  }
  __syncthreads();

  // phase 6: greedy sorted NMS scan, wave 0. Selected list in registers:
  // lane L owns selections L, L+64, L+128, L+192 (box + cached area).
  // 2-candidate lookahead: candidates c and c+1 are tested against the
  // selected set in one instruction stream; c+1 additionally vs c iff c
  // was selected — exact serial-greedy semantics, half the loop overhead.
  if (tid < 64) {
    int lane = tid;
    float b0x=0,b0y=0,b0z=0,b0w=0, b1x=0,b1y=0,b1z=0,b1w=0;
    float b2x=0,b2y=0,b2z=0,b2w=0, b3x=0,b3y=0,b3z=0,b3w=0;
    float ar0=0, ar1=0, ar2=0, ar3=0;
    unsigned int i0=0,i1=0,i2=0,i3=0;
    float s0=0,s1=0,s2=0,s3=0;
    int nsel = 0;

    auto insert_sel = [&](unsigned long long key, float4 box, float area) {
      if (lane == (nsel & 63)) {
        unsigned int idx = ~(unsigned int)(key & 0xFFFFFFFFull);
        float sc = __uint_as_float((unsigned int)(key >> 32));
        int slot = nsel >> 6;
        if (slot == 0)      { b0x=box.x; b0y=box.y; b0z=box.z; b0w=box.w; ar0=area; i0=idx; s0=sc; }
        else if (slot == 1) { b1x=box.x; b1y=box.y; b1z=box.z; b1w=box.w; ar1=area; i1=idx; s1=sc; }
        else if (slot == 2) { b2x=box.x; b2y=box.y; b2z=box.z; b2w=box.w; ar2=area; i2=idx; s2=sc; }
        else                { b3x=box.x; b3y=box.y; b3z=box.z; b3w=box.w; ar3=area; i3=idx; s3=sc; }
      }
      nsel++;
    };

    if (cnt > 0) {
      unsigned long long kA = keys[0], kB;
      float4 bA = cbox[0], bB;
      { int j1 = (1 < cnt) ? 1 : 0; kB = keys[j1]; bB = cbox[j1]; }
      for (int c = 0; c < cnt && nsel < TOPK; c += 2) {
        unsigned long long keyA = kA; float4 boxA = bA;
        unsigned long long keyB = kB; float4 boxB = bB;
        int p2 = (c + 2 < cnt) ? c + 2 : 0;
        int p3 = (c + 3 < cnt) ? c + 3 : 0;
        kA = keys[p2]; bA = cbox[p2];
        kB = keys[p3]; bB = cbox[p3];
        bool hasB = (c + 1 < cnt);
        float areaA = (boxA.z - boxA.x) * (boxA.w - boxA.y);
        float areaB = (boxB.z - boxB.x) * (boxB.w - boxB.y);
        bool supA = false, supB = false;
        if (lane < nsel) {
          supA |= iou_chk(b0x,b0y,b0z,b0w,ar0, boxA.x,boxA.y,boxA.z,boxA.w,areaA);
          supB |= iou_chk(b0x,b0y,b0z,b0w,ar0, boxB.x,boxB.y,boxB.z,boxB.w,areaB);
        }
        if (64 + lane < nsel) {
          supA |= iou_chk(b1x,b1y,b1z,b1w,ar1, boxA.x,boxA.y,boxA.z,boxA.w,areaA);
          supB |= iou_chk(b1x,b1y,b1z,b1w,ar1, boxB.x,boxB.y,boxB.z,boxB.w,areaB);
        }
        if (128 + lane < nsel) {
          supA |= iou_chk(b2x,b2y,b2z,b2w,ar2, boxA.x,boxA.y,boxA.z,boxA.w,areaA);
          supB |= iou_chk(b2x,b2y,b2z,b2w,ar2, boxB.x,boxB.y,boxB.z,boxB.w,areaB);
        }
        if (192 + lane < nsel) {
          supA |= iou_chk(b3x,b3y,b3z,b3w,ar3, boxA.x,boxA.y,boxA.z,boxA.w,areaA);
          supB |= iou_chk(b3x,b3y,b3z,b3w,ar3, boxB.x,boxB.y,boxB.z,boxB.w,areaB);
        }
        bool selA   = !__any(supA ? 1 : 0);
        bool supBany = __any(supB ? 1 : 0);
        if (selA) {
          insert_sel(keyA, boxA, areaA);
          if (hasB && nsel < TOPK) {
            bool ab = iou_chk(boxA.x,boxA.y,boxA.z,boxA.w, areaA,
                              boxB.x,boxB.y,boxB.z,boxB.w, areaB);
            if (!supBany && !ab) insert_sel(keyB, boxB, areaB);
          }
        } else {
          if (hasB && !supBany) insert_sel(keyB, boxB, areaB);
        }
      }
    }

    if (lane < nsel)       { int r = lane;     selb[r*5+0]=b0x; selb[r*5+1]=b0y; selb[r*5+2]=b0z; selb[r*5+3]=b0w; sel_idx[r]=i0; sel_score[r]=s0; }
    if (64 + lane < nsel)  { int r = 64+lane;  selb[r*5+0]=b1x; selb[r*5+1]=b1y; selb[r*5+2]=b1z; selb[r*5+3]=b1w; sel_idx[r]=i1; sel_score[r]=s1; }
    if (128 + lane < nsel) { int r = 128+lane; selb[r*5+0]=b2x; selb[r*5+1]=b2y; selb[r*5+2]=b2z; selb[r*5+3]=b2w; sel_idx[r]=i2; sel_score[r]=s2; }
    if (192 + lane < nsel) { int r = 192+lane; selb[r*5+0]=b3x; selb[r*5+1]=b3y; selb[r*5+2]=b3z; selb[r*5+3]=b3w; sel_idx[r]=i3; sel_score[r]=s3; }
    if (lane == 0) s_nsel = nsel;
  }
  __syncthreads();

  // phase 7: output rows [class_id, conf, xmin, ymin, xmax, ymax]
  int nsel = s_nsel;
  for (int e = tid; e < TOPK * 6; e += 1024) {
    int r = e / 6, col = e % 6;
    float val = 0.0f;
    if (r < nsel) {
      if (col == 0)      val = cls[base + sel_idx[r]];
      else if (col == 1) val = sel_score[r];
      else               val = selb[r * 5 + (col - 2)];
    }
    out[(size_t)b * (TOPK * 6) + e] = val;
  }
}

// ---------------------------------------------------------------- launch ----
extern "C" void kernel_launch(void* const* d_in, const int* in_sizes, int n_in,
                              void* d_out, int out_size, void* d_ws, size_t ws_size,
                              hipStream_t stream) {
  const float* yp = (const float*)d_in[0];
  float* out = (float*)d_out;
  char* ws = (char*)d_ws;

  const int total_anch = NANCH * NBATCH;              // 786048
  float4* boxes = (float4*)ws;
  float* scores = (float*)(ws + (size_t)total_anch * 16);
  float* cls    = (float*)(ws + (size_t)total_anch * 16 + (size_t)total_anch * 4);

  const int nblk = total_anch / APB;                  // 12282, exact
  decode_kernel<<<nblk, 256, 0, stream>>>(yp, boxes, scores, cls);
  nms_kernel<<<NBATCH, 1024, 0, stream>>>(boxes, scores, cls, out);
}

// Round 2
// 446.503 us; speedup vs baseline: 1.1523x; 1.1523x over previous
//
#include <hip/hip_runtime.h>
#include <stdint.h>

#define NANCH 24564
#define NBATCH 32
#define NCLS 81
#define FEAT 93
#define NEGV -10000000000.0f
#define CONF_T 0.01f
#define IOU_T 0.45f
#define TOPK 200
#define CAP 1024
#define TARGET 768u
#define NBINS 1024
#define APB 64   // anchors per decode block
#define NF4 (APB * FEAT / 4)   // 1488 float4 per block

// ---------------------------------------------------------------- decode ----
// 256 threads, 64 anchors/block. Staging via global_load_lds (direct DMA,
// no VGPR round-trip). Then 4 lanes per anchor for the 81-class argmax,
// merged via __shfl_xor with the first-index tie rule (matches jnp.argmax).
__global__ __launch_bounds__(256) void decode_kernel(
    const float* __restrict__ yp, float4* __restrict__ boxes,
    float* __restrict__ scores, float* __restrict__ cls) {
#pragma clang fp contract(off)
  __shared__ float lds[APB * FEAT];   // 23808 B
  const float* src = yp + (size_t)blockIdx.x * (APB * FEAT);

  // global->LDS DMA: element i lands at LDS byte i*16; HW dest is
  // wave-uniform base (i&~63)*16 + lane*16, and i - (i&~63) == lane. exact.
  for (int i = threadIdx.x; i < NF4; i += 256) {
    int wb = i & ~63;   // wave-uniform
    __builtin_amdgcn_global_load_lds(
        (const __attribute__((address_space(1))) void*)(src + (size_t)i * 4),
        (__attribute__((address_space(3))) void*)(lds + wb * 4),
        16, 0, 0);
  }
  __syncthreads();   // compiler drains vmcnt before s_barrier

  const int L = threadIdx.x;
  const int a = L >> 2;          // anchor within block
  const int part = L & 3;
  const float* p = &lds[a * FEAT];

  int c0 = part * 21;
  int c1 = (part == 3) ? NCLS : c0 + 21;
  float best = -3.0e38f;
  int bi = c0;
  for (int c = c0; c < c1; ++c) {  // strict > keeps first index within part
    float v = p[c];
    if (v > best) { best = v; bi = c; }
  }
  // merge 4 parts: smaller index wins ties (parts are index-ordered)
  for (int off = 1; off < 4; off <<= 1) {
    float ov = __shfl_xor(best, off, 64);
    int   oi = __shfl_xor(bi, off, 64);
    if (ov > best || (ov == best && oi < bi)) { best = ov; bi = oi; }
  }

  if (part == 0) {
    float cx = p[81] * p[89] * p[87] + p[85];
    float cy = p[82] * p[90] * p[88] + p[86];
    float w  = expf(p[83] * p[91]) * p[87];
    float h  = expf(p[84] * p[92]) * p[88];
    float xmin = (cx - 0.5f * w) * 512.0f;
    float ymin = (cy - 0.5f * h) * 512.0f;
    float xmax = (cx + 0.5f * w) * 512.0f;
    float ymax = (cy + 0.5f * h) * 512.0f;
    int ga = blockIdx.x * APB + a;
    boxes[ga] = make_float4(xmin, ymin, xmax, ymax);
    cls[ga] = (float)bi;
    scores[ga] = (bi != 0 && best > CONF_T) ? best : NEGV;
  }
}

// IoU with reference op order (f32 divide, exact reference semantics).
// Symmetric in (s,b): fmax/fmin symmetric, f32 add commutative.
__device__ __forceinline__ bool iou_gt(float sx1, float sy1, float sx2, float sy2,
                                       float bx1, float by1, float bx2, float by2) {
#pragma clang fp contract(off)
  float ix1 = fmaxf(sx1, bx1);
  float iy1 = fmaxf(sy1, by1);
  float ix2 = fminf(sx2, bx2);
  float iy2 = fminf(sy2, by2);
  float inter = fmaxf(ix2 - ix1, 0.0f) * fmaxf(iy2 - iy1, 0.0f);
  float area_s = (sx2 - sx1) * (sy2 - sy1);
  float area_b = (bx2 - bx1) * (by2 - by1);
  float uni = area_s + area_b - inter;
  float iou = (uni > 0.0f) ? (inter / uni) : 0.0f;
  return iou > IOU_T;
}

__device__ __forceinline__ unsigned long long maxu64(unsigned long long a, unsigned long long b) { return a > b ? a : b; }
__device__ __forceinline__ unsigned long long minu64(unsigned long long a, unsigned long long b) { return a < b ? a : b; }

// ------------------------------------------------------------------- nms ----
__global__ __launch_bounds__(1024) void nms_kernel(
    const float4* __restrict__ boxes, const float* __restrict__ scores,
    const float* __restrict__ cls, float* __restrict__ out) {
#pragma clang fp contract(off)
  __shared__ unsigned long long keys[CAP];   // 8 KB
  __shared__ float4 cbox[CAP];               // 16 KB
  __shared__ unsigned int hist[NBINS];       // 4 KB
  __shared__ unsigned long long tmat[256 * 4];  // 8 KB within-tile bit matrix
  __shared__ unsigned char psup4[4][256];    // 1 KB prior-selection suppression
  __shared__ float selb[TOPK * 5];
  __shared__ unsigned int sel_idx[TOPK];
  __shared__ float sel_score[TOPK];
  __shared__ unsigned int s_cnt;
  __shared__ int s_cutoff;
  __shared__ int s_nsel;

  const int b = blockIdx.x;
  const int tid = threadIdx.x;
  const size_t base = (size_t)b * NANCH;

  // phase 0: load 24 scores into registers (single global pass)
  float sreg[24];
#pragma unroll
  for (int j = 0; j < 24; ++j) {
    int i = tid + j * 1024;
    sreg[j] = (i < NANCH) ? scores[base + i] : NEGV;
  }

  // phase 1: histogram
  hist[tid] = 0u;
  if (tid == 0) { s_cnt = 0u; s_cutoff = 0; s_nsel = 0; }
  __syncthreads();
#pragma unroll
  for (int j = 0; j < 24; ++j) {
    float s = sreg[j];
    if (s >= 0.0f) {
      int bin = (int)(s * ((float)NBINS / 6.0f));
      bin = bin > (NBINS - 1) ? (NBINS - 1) : bin;
      atomicAdd(&hist[bin], 1u);
    }
  }
  __syncthreads();

  // phase 2: suffix-inclusive sums over 1024 bins, wave 0 only (shuffle scan)
  if (tid < 64) {
    int lane = tid;
    unsigned int h[16];
    unsigned int S = 0;
#pragma unroll
    for (int t = 0; t < 16; ++t) { h[t] = hist[lane * 16 + t]; S += h[t]; }
    unsigned int incl = S;
    for (int off = 1; off < 64; off <<= 1) {
      unsigned int o = __shfl_down(incl, off, 64);
      if (lane + off < 64) incl += o;
    }
    unsigned int acc = incl - S;   // exclusive suffix
#pragma unroll
    for (int t = 15; t >= 0; --t) { acc += h[t]; hist[lane * 16 + t] = acc; }
  }
  __syncthreads();
  {
    unsigned int sfx = hist[tid];
    unsigned int nxt = (tid < NBINS - 1) ? hist[tid + 1] : 0u;
    if (sfx >= TARGET && nxt < TARGET) s_cutoff = tid;   // unique writer
  }
  __syncthreads();
  float cutoffv = (float)s_cutoff * (6.0f / (float)NBINS);

  // phase 3: compact candidates >= cutoff from registers
#pragma unroll
  for (int j = 0; j < 24; ++j) {
    float s = sreg[j];
    if (s >= cutoffv) {   // NEGV always excluded
      unsigned int pos = atomicAdd(&s_cnt, 1u);
      if (pos < CAP) {
        unsigned int i = (unsigned int)(tid + j * 1024);
        keys[pos] = ((unsigned long long)__float_as_uint(s) << 32) |
                    (unsigned long long)(~i);
      }
    }
  }
  __syncthreads();
  int cnt = (int)(s_cnt > CAP ? CAP : s_cnt);

  // phase 4: hybrid bitonic sort (descending), 1 elem/thread.
  // j<64 steps: wave-local via 64-bit shfl_xor (no barrier). j>=64: LDS.
  unsigned long long v = (tid < cnt) ? keys[tid] : 0ull;
  for (int k = 2; k <= 64; k <<= 1) {
    for (int j = k >> 1; j >= 1; j >>= 1) {
      unsigned long long o = __shfl_xor((long long)v, j, 64);
      bool keepmax = (((tid & k) == 0) == ((tid & j) == 0));
      v = keepmax ? maxu64(v, o) : minu64(v, o);
    }
  }
  for (int k = 128; k <= CAP; k <<= 1) {
    for (int j = k >> 1; j >= 64; j >>= 1) {
      keys[tid] = v;
      __syncthreads();
      unsigned long long o = keys[tid ^ j];
      bool keepmax = (((tid & k) == 0) == ((tid & j) == 0));
      v = keepmax ? maxu64(v, o) : minu64(v, o);
      __syncthreads();
    }
    for (int j = 32; j >= 1; j >>= 1) {
      unsigned long long o = __shfl_xor((long long)v, j, 64);
      bool keepmax = (((tid & k) == 0) == ((tid & j) == 0));
      v = keepmax ? maxu64(v, o) : minu64(v, o);
    }
  }
  keys[tid] = v;
  __syncthreads();

  // phase 5: prefetch candidate boxes into LDS
  if (v != 0ull) {
    unsigned int idx = ~(unsigned int)(v & 0xFFFFFFFFull);
    cbox[tid] = boxes[base + idx];
  }
  __syncthreads();

  // phase 6: tiled parallel greedy NMS — identical result to the sequential
  // greedy scan (candidate c suppressed iff some SELECTED c' < c overlaps).
  // Per 256-candidate tile:
  //   A) parallel: byte flags "suppressed by a prior-tile selection"
  //      (vs selb[0..nsel), 4-way split over s, no atomics)
  //   B) parallel: within-tile 256x256 overlap bit matrix; thread (w, j)
  //      computes word w of row j (i < j only), plain write, no atomics
  //   C) wave-0 resolve: rows in registers, selmask in registers, one
  //      __ballot per candidate — no IoU in the serial chain.
  for (int t = 0; t < 4; ++t) {
    int lo = t * 256;
    if (lo >= cnt) break;
    int tlen = cnt - lo; if (tlen > 256) tlen = 256;
    int nprior = s_nsel;
    if (nprior >= TOPK) break;

    // A: prior-selection suppression flags
    {
      int c = tid & 255;
      int s0 = tid >> 8;
      bool sup = false;
      if (c < tlen && nprior > 0) {
        float4 cb = cbox[lo + c];
        for (int s = s0; s < nprior; s += 4)
          sup |= iou_gt(selb[s * 5 + 0], selb[s * 5 + 1],
                        selb[s * 5 + 2], selb[s * 5 + 3],
                        cb.x, cb.y, cb.z, cb.w);
      }
      psup4[s0][c] = sup ? (unsigned char)1 : (unsigned char)0;
    }

    // B: within-tile bit matrix (row j, word w: bits i = w*64+l, i < j)
    {
      int w = tid >> 8;          // 0..3
      int j = tid & 255;
      unsigned long long bits = 0ull;
      if (j < tlen) {
        float4 bj = cbox[lo + j];
        int ibeg = w * 64;
        int iend = ibeg + 64; if (iend > j) iend = j;
        for (int i = ibeg; i < iend; ++i) {
          float4 bi = cbox[lo + i];   // same addr across wave -> broadcast
          if (iou_gt(bi.x, bi.y, bi.z, bi.w, bj.x, bj.y, bj.z, bj.w))
            bits |= 1ull << (i & 63);
        }
      }
      tmat[j * 4 + w] = bits;
    }
    __syncthreads();

    // C: resolve on wave 0
    if (tid < 64) {
      int lane = tid;
      unsigned long long m0 = 0ull, m1 = 0ull, m2 = 0ull, m3 = 0ull;
      int nsel = nprior;

#define RESOLVE_SLOT(SLOT, MWORD)                                              \
      if ((SLOT) * 64 < tlen && nsel < TOPK) {                                 \
        const int cbase = (SLOT) * 64;                                         \
        unsigned long long ra = tmat[(cbase + lane) * 4 + 0];                  \
        unsigned long long rb = tmat[(cbase + lane) * 4 + 1];                  \
        unsigned long long rc = tmat[(cbase + lane) * 4 + 2];                  \
        unsigned long long rd = tmat[(cbase + lane) * 4 + 3];                  \
        bool mypsup = (psup4[0][cbase + lane] | psup4[1][cbase + lane] |       \
                       psup4[2][cbase + lane] | psup4[3][cbase + lane]) != 0;  \
        int cend = tlen - cbase; if (cend > 64) cend = 64;                     \
        for (int cc = 0; cc < cend && nsel < TOPK; ++cc) {                     \
          bool sup = mypsup |                                                  \
              (((ra & m0) | (rb & m1) | (rc & m2) | (rd & m3)) != 0ull);       \
          unsigned long long voted = __ballot(sup ? 1 : 0);                    \
          if (!((voted >> cc) & 1ull)) {                                       \
            MWORD |= 1ull << cc;                                               \
            if (lane == cc) {                                                  \
              int gc = lo + cbase + cc;                                        \
              float4 bx = cbox[gc];                                            \
              unsigned long long key = keys[gc];                               \
              selb[nsel * 5 + 0] = bx.x; selb[nsel * 5 + 1] = bx.y;            \
              selb[nsel * 5 + 2] = bx.z; selb[nsel * 5 + 3] = bx.w;            \
              sel_idx[nsel]   = ~(unsigned int)(key & 0xFFFFFFFFull);          \
              sel_score[nsel] = __uint_as_float((unsigned int)(key >> 32));    \
            }                                                                  \
            nsel++;                                                            \
          }                                                                    \
        }                                                                      \
      }

      RESOLVE_SLOT(0, m0)
      RESOLVE_SLOT(1, m1)
      RESOLVE_SLOT(2, m2)
      RESOLVE_SLOT(3, m3)
#undef RESOLVE_SLOT

      if (lane == 0) s_nsel = nsel;
    }
    __syncthreads();
  }

  // phase 7: output rows [class_id, conf, xmin, ymin, xmax, ymax]
  int nsel = s_nsel;
  for (int e = tid; e < TOPK * 6; e += 1024) {
    int r = e / 6, col = e % 6;
    float val = 0.0f;
    if (r < nsel) {
      if (col == 0)      val = cls[base + sel_idx[r]];
      else if (col == 1) val = sel_score[r];
      else               val = selb[r * 5 + (col - 2)];
    }
    out[(size_t)b * (TOPK * 6) + e] = val;
  }
}

// ---------------------------------------------------------------- launch ----
extern "C" void kernel_launch(void* const* d_in, const int* in_sizes, int n_in,
                              void* d_out, int out_size, void* d_ws, size_t ws_size,
                              hipStream_t stream) {
  const float* yp = (const float*)d_in[0];
  float* out = (float*)d_out;
  char* ws = (char*)d_ws;

  const int total_anch = NANCH * NBATCH;              // 786048
  float4* boxes = (float4*)ws;
  float* scores = (float*)(ws + (size_t)total_anch * 16);
  float* cls    = (float*)(ws + (size_t)total_anch * 16 + (size_t)total_anch * 4);

  const int nblk = total_anch / APB;                  // 12282, exact
  decode_kernel<<<nblk, 256, 0, stream>>>(yp, boxes, scores, cls);
  nms_kernel<<<NBATCH, 1024, 0, stream>>>(boxes, scores, cls, out);
}

// Round 3
// 443.641 us; speedup vs baseline: 1.1597x; 1.0065x over previous
//
#include <hip/hip_runtime.h>
#include <stdint.h>

#define NANCH 24564
#define NBATCH 32
#define NCLS 81
#define FEAT 93
#define NEGV -10000000000.0f
#define CONF_T 0.01f
#define IOU_T 0.45f
#define TOPK 200
#define CAP 1024
#define TARGET 768u
#define NBINS 1024
#define APB 64   // anchors per decode block
#define NF4 (APB * FEAT / 4)   // 1488 float4 per block

// ---------------------------------------------------------------- decode ----
// 256 threads, 64 anchors/block. Staging via global_load_lds (direct DMA,
// no VGPR round-trip). Then 4 lanes per anchor for the 81-class argmax,
// merged via __shfl_xor with the first-index tie rule (matches jnp.argmax).
__global__ __launch_bounds__(256) void decode_kernel(
    const float* __restrict__ yp, float4* __restrict__ boxes,
    float* __restrict__ scores, float* __restrict__ cls) {
#pragma clang fp contract(off)
  __shared__ float lds[APB * FEAT];   // 23808 B
  const float* src = yp + (size_t)blockIdx.x * (APB * FEAT);

  // global->LDS DMA: element i lands at LDS byte i*16; HW dest is
  // wave-uniform base (i&~63)*16 + lane*16, and i - (i&~63) == lane. exact.
  for (int i = threadIdx.x; i < NF4; i += 256) {
    int wb = i & ~63;   // wave-uniform
    __builtin_amdgcn_global_load_lds(
        (const __attribute__((address_space(1))) void*)(src + (size_t)i * 4),
        (__attribute__((address_space(3))) void*)(lds + wb * 4),
        16, 0, 0);
  }
  __syncthreads();   // compiler drains vmcnt before s_barrier

  const int L = threadIdx.x;
  const int a = L >> 2;          // anchor within block
  const int part = L & 3;
  const float* p = &lds[a * FEAT];

  int c0 = part * 21;
  int c1 = (part == 3) ? NCLS : c0 + 21;
  float best = -3.0e38f;
  int bi = c0;
  for (int c = c0; c < c1; ++c) {  // strict > keeps first index within part
    float v = p[c];
    if (v > best) { best = v; bi = c; }
  }
  // merge 4 parts: smaller index wins ties (parts are index-ordered)
  for (int off = 1; off < 4; off <<= 1) {
    float ov = __shfl_xor(best, off, 64);
    int   oi = __shfl_xor(bi, off, 64);
    if (ov > best || (ov == best && oi < bi)) { best = ov; bi = oi; }
  }

  if (part == 0) {
    float cx = p[81] * p[89] * p[87] + p[85];
    float cy = p[82] * p[90] * p[88] + p[86];
    float w  = expf(p[83] * p[91]) * p[87];
    float h  = expf(p[84] * p[92]) * p[88];
    float xmin = (cx - 0.5f * w) * 512.0f;
    float ymin = (cy - 0.5f * h) * 512.0f;
    float xmax = (cx + 0.5f * w) * 512.0f;
    float ymax = (cy + 0.5f * h) * 512.0f;
    int ga = blockIdx.x * APB + a;
    boxes[ga] = make_float4(xmin, ymin, xmax, ymax);
    cls[ga] = (float)bi;
    scores[ga] = (bi != 0 && best > CONF_T) ? best : NEGV;
  }
}

// Exact division-free IoU threshold test (verified bit-exact on this input
// in an earlier passing run). RN_f32(inter/uni) > 0.45f  <=>  inter/uni > M
// where M = midpoint(0.45f, nextafter(0.45f,+inf)); tie-to-even at M rounds
// to 0.45f (even mantissa) so the boundary is strict. M has 25 mantissa
// bits, uni has <=24 -> M*uni is EXACT in f64, so the f64 compare is
// bit-equivalent to the reference's f32 divide-and-compare. Areas are
// cached (computed once with the reference op order), value-identical.
__device__ __forceinline__ bool iou_chk(float sx1, float sy1, float sx2, float sy2, float sarea,
                                        float bx1, float by1, float bx2, float by2, float barea) {
#pragma clang fp contract(off)
  float ix1 = fmaxf(sx1, bx1);
  float iy1 = fmaxf(sy1, by1);
  float ix2 = fminf(sx2, bx2);
  float iy2 = fminf(sy2, by2);
  float inter = fmaxf(ix2 - ix1, 0.0f) * fmaxf(iy2 - iy1, 0.0f);
  float uni = sarea + barea - inter;   // same f32 value as reference
  const double UMID = 0.5 * ((double)0.45f + (double)__uint_as_float(0x3EE66667u));
  return (uni > 0.0f) & ((double)inter > UMID * (double)uni);
}

__device__ __forceinline__ unsigned long long maxu64(unsigned long long a, unsigned long long b) { return a > b ? a : b; }
__device__ __forceinline__ unsigned long long minu64(unsigned long long a, unsigned long long b) { return a < b ? a : b; }

// ------------------------------------------------------------------- nms ----
__global__ __launch_bounds__(1024) void nms_kernel(
    const float4* __restrict__ boxes, const float* __restrict__ scores,
    const float* __restrict__ cls, float* __restrict__ out) {
#pragma clang fp contract(off)
  __shared__ unsigned long long keys[CAP];   // 8 KB
  __shared__ float4 cbox[CAP];               // 16 KB
  __shared__ float carea[CAP];               // 4 KB candidate areas
  __shared__ unsigned int hist[NBINS];       // 4 KB
  __shared__ unsigned long long tmat[256 * 4];  // 8 KB within-tile bit matrix
  __shared__ unsigned char psup4[4][256];    // 1 KB prior-selection suppression
  __shared__ float selb[TOPK * 5];
  __shared__ float selarea[TOPK];
  __shared__ unsigned int sel_idx[TOPK];
  __shared__ float sel_score[TOPK];
  __shared__ unsigned int s_cnt;
  __shared__ int s_cutoff;
  __shared__ int s_nsel;

  const int b = blockIdx.x;
  const int tid = threadIdx.x;
  const size_t base = (size_t)b * NANCH;

  // phase 0: load 24 scores into registers (single global pass)
  float sreg[24];
#pragma unroll
  for (int j = 0; j < 24; ++j) {
    int i = tid + j * 1024;
    sreg[j] = (i < NANCH) ? scores[base + i] : NEGV;
  }

  // phase 1: histogram
  hist[tid] = 0u;
  if (tid == 0) { s_cnt = 0u; s_cutoff = 0; s_nsel = 0; }
  __syncthreads();
#pragma unroll
  for (int j = 0; j < 24; ++j) {
    float s = sreg[j];
    if (s >= 0.0f) {
      int bin = (int)(s * ((float)NBINS / 6.0f));
      bin = bin > (NBINS - 1) ? (NBINS - 1) : bin;
      atomicAdd(&hist[bin], 1u);
    }
  }
  __syncthreads();

  // phase 2: suffix-inclusive sums over 1024 bins, wave 0 only (shuffle scan)
  if (tid < 64) {
    int lane = tid;
    unsigned int h[16];
    unsigned int S = 0;
#pragma unroll
    for (int t = 0; t < 16; ++t) { h[t] = hist[lane * 16 + t]; S += h[t]; }
    unsigned int incl = S;
    for (int off = 1; off < 64; off <<= 1) {
      unsigned int o = __shfl_down(incl, off, 64);
      if (lane + off < 64) incl += o;
    }
    unsigned int acc = incl - S;   // exclusive suffix
#pragma unroll
    for (int t = 15; t >= 0; --t) { acc += h[t]; hist[lane * 16 + t] = acc; }
  }
  __syncthreads();
  {
    unsigned int sfx = hist[tid];
    unsigned int nxt = (tid < NBINS - 1) ? hist[tid + 1] : 0u;
    if (sfx >= TARGET && nxt < TARGET) s_cutoff = tid;   // unique writer
  }
  __syncthreads();
  float cutoffv = (float)s_cutoff * (6.0f / (float)NBINS);

  // phase 3: compact candidates >= cutoff from registers
#pragma unroll
  for (int j = 0; j < 24; ++j) {
    float s = sreg[j];
    if (s >= cutoffv) {   // NEGV always excluded
      unsigned int pos = atomicAdd(&s_cnt, 1u);
      if (pos < CAP) {
        unsigned int i = (unsigned int)(tid + j * 1024);
        keys[pos] = ((unsigned long long)__float_as_uint(s) << 32) |
                    (unsigned long long)(~i);
      }
    }
  }
  __syncthreads();
  int cnt = (int)(s_cnt > CAP ? CAP : s_cnt);

  // phase 4: hybrid bitonic sort (descending), 1 elem/thread.
  // j<64 steps: wave-local via 64-bit shfl_xor (no barrier). j>=64: LDS.
  unsigned long long v = (tid < cnt) ? keys[tid] : 0ull;
  for (int k = 2; k <= 64; k <<= 1) {
    for (int j = k >> 1; j >= 1; j >>= 1) {
      unsigned long long o = __shfl_xor((long long)v, j, 64);
      bool keepmax = (((tid & k) == 0) == ((tid & j) == 0));
      v = keepmax ? maxu64(v, o) : minu64(v, o);
    }
  }
  for (int k = 128; k <= CAP; k <<= 1) {
    for (int j = k >> 1; j >= 64; j >>= 1) {
      keys[tid] = v;
      __syncthreads();
      unsigned long long o = keys[tid ^ j];
      bool keepmax = (((tid & k) == 0) == ((tid & j) == 0));
      v = keepmax ? maxu64(v, o) : minu64(v, o);
      __syncthreads();
    }
    for (int j = 32; j >= 1; j >>= 1) {
      unsigned long long o = __shfl_xor((long long)v, j, 64);
      bool keepmax = (((tid & k) == 0) == ((tid & j) == 0));
      v = keepmax ? maxu64(v, o) : minu64(v, o);
    }
  }
  keys[tid] = v;
  __syncthreads();

  // phase 5: prefetch candidate boxes into LDS + cache areas (reference op
  // order (x2-x1)*(y2-y1); value identical to per-pair recomputation)
  if (v != 0ull) {
    unsigned int idx = ~(unsigned int)(v & 0xFFFFFFFFull);
    float4 cb = boxes[base + idx];
    cbox[tid] = cb;
    carea[tid] = (cb.z - cb.x) * (cb.w - cb.y);
  }
  __syncthreads();

  // phase 6: tiled parallel greedy NMS — identical result to the sequential
  // greedy scan (candidate c suppressed iff some SELECTED c' < c overlaps).
  // Per 256-candidate tile:
  //   A) parallel: byte flags "suppressed by a prior-tile selection"
  //      (vs selb[0..nsel), 4-way split over s, no atomics)
  //   B) parallel: within-tile 256x256 overlap bit matrix; thread (w, j)
  //      computes word w of row j (i < j only), plain write, no atomics
  //   C) wave-0 resolve: rows in registers, selmask in registers, one
  //      __ballot per candidate — no IoU in the serial chain.
  for (int t = 0; t < 4; ++t) {
    int lo = t * 256;
    if (lo >= cnt) break;
    int tlen = cnt - lo; if (tlen > 256) tlen = 256;
    int nprior = s_nsel;
    if (nprior >= TOPK) break;

    // A: prior-selection suppression flags
    {
      int c = tid & 255;
      int s0 = tid >> 8;
      bool sup = false;
      if (c < tlen && nprior > 0) {
        float4 cb = cbox[lo + c];
        float ca = carea[lo + c];
        for (int s = s0; s < nprior; s += 4)
          sup |= iou_chk(selb[s * 5 + 0], selb[s * 5 + 1],
                         selb[s * 5 + 2], selb[s * 5 + 3], selarea[s],
                         cb.x, cb.y, cb.z, cb.w, ca);
      }
      psup4[s0][c] = sup ? (unsigned char)1 : (unsigned char)0;
    }

    // B: within-tile bit matrix (row j, word w: bits i = w*64+l, i < j)
    {
      int w = tid >> 8;          // 0..3
      int j = tid & 255;
      unsigned long long bits = 0ull;
      if (j < tlen) {
        float4 bj = cbox[lo + j];
        float aj = carea[lo + j];
        int ibeg = w * 64;
        int iend = ibeg + 64; if (iend > j) iend = j;
        for (int i = ibeg; i < iend; ++i) {
          float4 bi = cbox[lo + i];   // same addr across wave -> broadcast
          float ai = carea[lo + i];
          if (iou_chk(bi.x, bi.y, bi.z, bi.w, ai, bj.x, bj.y, bj.z, bj.w, aj))
            bits |= 1ull << (i & 63);
        }
      }
      tmat[j * 4 + w] = bits;
    }
    __syncthreads();

    // C: resolve on wave 0
    if (tid < 64) {
      int lane = tid;
      unsigned long long m0 = 0ull, m1 = 0ull, m2 = 0ull, m3 = 0ull;
      int nsel = nprior;

#define RESOLVE_SLOT(SLOT, MWORD)                                              \
      if ((SLOT) * 64 < tlen && nsel < TOPK) {                                 \
        const int cbase = (SLOT) * 64;                                         \
        unsigned long long ra = tmat[(cbase + lane) * 4 + 0];                  \
        unsigned long long rb = tmat[(cbase + lane) * 4 + 1];                  \
        unsigned long long rc = tmat[(cbase + lane) * 4 + 2];                  \
        unsigned long long rd = tmat[(cbase + lane) * 4 + 3];                  \
        bool mypsup = (psup4[0][cbase + lane] | psup4[1][cbase + lane] |       \
                       psup4[2][cbase + lane] | psup4[3][cbase + lane]) != 0;  \
        int cend = tlen - cbase; if (cend > 64) cend = 64;                     \
        for (int cc = 0; cc < cend && nsel < TOPK; ++cc) {                     \
          bool sup = mypsup |                                                  \
              (((ra & m0) | (rb & m1) | (rc & m2) | (rd & m3)) != 0ull);       \
          unsigned long long voted = __ballot(sup ? 1 : 0);                    \
          if (!((voted >> cc) & 1ull)) {                                       \
            MWORD |= 1ull << cc;                                               \
            if (lane == cc) {                                                  \
              int gc = lo + cbase + cc;                                        \
              float4 bx = cbox[gc];                                            \
              unsigned long long key = keys[gc];                               \
              selb[nsel * 5 + 0] = bx.x; selb[nsel * 5 + 1] = bx.y;            \
              selb[nsel * 5 + 2] = bx.z; selb[nsel * 5 + 3] = bx.w;            \
              selarea[nsel]   = carea[gc];                                     \
              sel_idx[nsel]   = ~(unsigned int)(key & 0xFFFFFFFFull);          \
              sel_score[nsel] = __uint_as_float((unsigned int)(key >> 32));    \
            }                                                                  \
            nsel++;                                                            \
          }                                                                    \
        }                                                                      \
      }

      RESOLVE_SLOT(0, m0)
      RESOLVE_SLOT(1, m1)
      RESOLVE_SLOT(2, m2)
      RESOLVE_SLOT(3, m3)
#undef RESOLVE_SLOT

      if (lane == 0) s_nsel = nsel;
    }
    __syncthreads();
  }

  // phase 7: output rows [class_id, conf, xmin, ymin, xmax, ymax]
  int nsel = s_nsel;
  for (int e = tid; e < TOPK * 6; e += 1024) {
    int r = e / 6, col = e % 6;
    float val = 0.0f;
    if (r < nsel) {
      if (col == 0)      val = cls[base + sel_idx[r]];
      else if (col == 1) val = sel_score[r];
      else               val = selb[r * 5 + (col - 2)];
    }
    out[(size_t)b * (TOPK * 6) + e] = val;
  }
}

// ---------------------------------------------------------------- launch ----
extern "C" void kernel_launch(void* const* d_in, const int* in_sizes, int n_in,
                              void* d_out, int out_size, void* d_ws, size_t ws_size,
                              hipStream_t stream) {
  const float* yp = (const float*)d_in[0];
  float* out = (float*)d_out;
  char* ws = (char*)d_ws;

  const int total_anch = NANCH * NBATCH;              // 786048
  float4* boxes = (float4*)ws;
  float* scores = (float*)(ws + (size_t)total_anch * 16);
  float* cls    = (float*)(ws + (size_t)total_anch * 16 + (size_t)total_anch * 4);

  const int nblk = total_anch / APB;                  // 12282, exact
  decode_kernel<<<nblk, 256, 0, stream>>>(yp, boxes, scores, cls);
  nms_kernel<<<NBATCH, 1024, 0, stream>>>(boxes, scores, cls, out);
}

// Round 4
// 440.211 us; speedup vs baseline: 1.1688x; 1.0078x over previous
//
#include <hip/hip_runtime.h>
#include <stdint.h>

#define NANCH 24564
#define NBATCH 32
#define NCLS 81
#define FEAT 93
#define NEGV -10000000000.0f
#define CONF_T 0.01f
#define IOU_T 0.45f
#define TOPK 200
#define CAP 1024
#define TARGET 768u
#define NBINS 1024
#define APB 64   // anchors per decode block
#define NF4 (APB * FEAT / 4)   // 1488 float4 per block

// ---------------------------------------------------------------- decode ----
// 256 threads, 64 anchors/block. Staging via global_load_lds (direct DMA,
// no VGPR round-trip). Then 4 lanes per anchor for the 81-class argmax,
// merged via __shfl_xor with the first-index tie rule (matches jnp.argmax).
__global__ __launch_bounds__(256) void decode_kernel(
    const float* __restrict__ yp, float4* __restrict__ boxes,
    float* __restrict__ scores, float* __restrict__ cls) {
#pragma clang fp contract(off)
  __shared__ float lds[APB * FEAT];   // 23808 B
  const float* src = yp + (size_t)blockIdx.x * (APB * FEAT);

  // global->LDS DMA: element i lands at LDS byte i*16; HW dest is
  // wave-uniform base (i&~63)*16 + lane*16, and i - (i&~63) == lane. exact.
  for (int i = threadIdx.x; i < NF4; i += 256) {
    int wb = i & ~63;   // wave-uniform
    __builtin_amdgcn_global_load_lds(
        (const __attribute__((address_space(1))) void*)(src + (size_t)i * 4),
        (__attribute__((address_space(3))) void*)(lds + wb * 4),
        16, 0, 0);
  }
  __syncthreads();   // compiler drains vmcnt before s_barrier

  const int L = threadIdx.x;
  const int a = L >> 2;          // anchor within block
  const int part = L & 3;
  const float* p = &lds[a * FEAT];

  int c0 = part * 21;
  int c1 = (part == 3) ? NCLS : c0 + 21;
  float best = -3.0e38f;
  int bi = c0;
  for (int c = c0; c < c1; ++c) {  // strict > keeps first index within part
    float v = p[c];
    if (v > best) { best = v; bi = c; }
  }
  // merge 4 parts: smaller index wins ties (parts are index-ordered)
  for (int off = 1; off < 4; off <<= 1) {
    float ov = __shfl_xor(best, off, 64);
    int   oi = __shfl_xor(bi, off, 64);
    if (ov > best || (ov == best && oi < bi)) { best = ov; bi = oi; }
  }

  if (part == 0) {
    float cx = p[81] * p[89] * p[87] + p[85];
    float cy = p[82] * p[90] * p[88] + p[86];
    float w  = expf(p[83] * p[91]) * p[87];
    float h  = expf(p[84] * p[92]) * p[88];
    float xmin = (cx - 0.5f * w) * 512.0f;
    float ymin = (cy - 0.5f * h) * 512.0f;
    float xmax = (cx + 0.5f * w) * 512.0f;
    float ymax = (cy + 0.5f * h) * 512.0f;
    int ga = blockIdx.x * APB + a;
    boxes[ga] = make_float4(xmin, ymin, xmax, ymax);
    cls[ga] = (float)bi;
    scores[ga] = (bi != 0 && best > CONF_T) ? best : NEGV;
  }
}

// Exact division-free IoU threshold test (bit-exact vs reference; verified
// absmax 0.0 in rounds 1 and 3). RN_f32(inter/uni) > 0.45f <=> inter/uni > M
// where M = midpoint(0.45f, nextafter(0.45f,+inf)); tie-to-even at M rounds
// to 0.45f (even mantissa) so the boundary is strict. M has 25 mantissa
// bits, uni has <=24 -> M*uni is EXACT in f64, so the f64 compare is
// bit-equivalent to the reference's f32 divide-and-compare. Areas are
// cached (computed once with the reference op order), value-identical.
__device__ __forceinline__ bool iou_chk(float sx1, float sy1, float sx2, float sy2, float sarea,
                                        float bx1, float by1, float bx2, float by2, float barea) {
#pragma clang fp contract(off)
  float ix1 = fmaxf(sx1, bx1);
  float iy1 = fmaxf(sy1, by1);
  float ix2 = fminf(sx2, bx2);
  float iy2 = fminf(sy2, by2);
  float inter = fmaxf(ix2 - ix1, 0.0f) * fmaxf(iy2 - iy1, 0.0f);
  float uni = sarea + barea - inter;   // same f32 value as reference
  const double UMID = 0.5 * ((double)0.45f + (double)__uint_as_float(0x3EE66667u));
  return (uni > 0.0f) & ((double)inter > UMID * (double)uni);
}

__device__ __forceinline__ unsigned long long maxu64(unsigned long long a, unsigned long long b) { return a > b ? a : b; }
__device__ __forceinline__ unsigned long long minu64(unsigned long long a, unsigned long long b) { return a < b ? a : b; }

// ------------------------------------------------------------------- nms ----
__global__ __launch_bounds__(1024) void nms_kernel(
    const float4* __restrict__ boxes, const float* __restrict__ scores,
    const float* __restrict__ cls, float* __restrict__ out) {
#pragma clang fp contract(off)
  __shared__ unsigned long long keys[CAP];   // 8 KB
  __shared__ float4 cbox[CAP];               // 16 KB
  __shared__ float carea[CAP];               // 4 KB candidate areas
  __shared__ unsigned int hist[NBINS];       // 4 KB
  __shared__ unsigned long long tmat[256 * 4];  // 8 KB within-tile bit matrix
  __shared__ unsigned char psup4[4][256];    // 1 KB prior-selection suppression
  __shared__ float selb[TOPK * 5];
  __shared__ float selarea[TOPK];
  __shared__ unsigned int sel_idx[TOPK];
  __shared__ float sel_score[TOPK];
  __shared__ unsigned int s_cnt;
  __shared__ int s_cutoff;
  __shared__ int s_nsel;

  const int b = blockIdx.x;
  const int tid = threadIdx.x;
  const size_t base = (size_t)b * NANCH;

  // phase 0: load 24 scores into registers (single global pass)
  float sreg[24];
#pragma unroll
  for (int j = 0; j < 24; ++j) {
    int i = tid + j * 1024;
    sreg[j] = (i < NANCH) ? scores[base + i] : NEGV;
  }

  // phase 1: histogram
  hist[tid] = 0u;
  if (tid == 0) { s_cnt = 0u; s_cutoff = 0; s_nsel = 0; }
  __syncthreads();
#pragma unroll
  for (int j = 0; j < 24; ++j) {
    float s = sreg[j];
    if (s >= 0.0f) {
      int bin = (int)(s * ((float)NBINS / 6.0f));
      bin = bin > (NBINS - 1) ? (NBINS - 1) : bin;
      atomicAdd(&hist[bin], 1u);
    }
  }
  __syncthreads();

  // phase 2: suffix-inclusive sums over 1024 bins, wave 0 only (shuffle scan)
  if (tid < 64) {
    int lane = tid;
    unsigned int h[16];
    unsigned int S = 0;
#pragma unroll
    for (int t = 0; t < 16; ++t) { h[t] = hist[lane * 16 + t]; S += h[t]; }
    unsigned int incl = S;
    for (int off = 1; off < 64; off <<= 1) {
      unsigned int o = __shfl_down(incl, off, 64);
      if (lane + off < 64) incl += o;
    }
    unsigned int acc = incl - S;   // exclusive suffix
#pragma unroll
    for (int t = 15; t >= 0; --t) { acc += h[t]; hist[lane * 16 + t] = acc; }
  }
  __syncthreads();
  {
    unsigned int sfx = hist[tid];
    unsigned int nxt = (tid < NBINS - 1) ? hist[tid + 1] : 0u;
    if (sfx >= TARGET && nxt < TARGET) s_cutoff = tid;   // unique writer
  }
  __syncthreads();
  float cutoffv = (float)s_cutoff * (6.0f / (float)NBINS);

  // phase 3: compact candidates >= cutoff from registers
#pragma unroll
  for (int j = 0; j < 24; ++j) {
    float s = sreg[j];
    if (s >= cutoffv) {   // NEGV always excluded
      unsigned int pos = atomicAdd(&s_cnt, 1u);
      if (pos < CAP) {
        unsigned int i = (unsigned int)(tid + j * 1024);
        keys[pos] = ((unsigned long long)__float_as_uint(s) << 32) |
                    (unsigned long long)(~i);
      }
    }
  }
  __syncthreads();
  int cnt = (int)(s_cnt > CAP ? CAP : s_cnt);

  // phase 4: hybrid bitonic sort (descending), 1 elem/thread.
  // j<64 steps: wave-local via 64-bit shfl_xor (no barrier). j>=64: LDS.
  unsigned long long v = (tid < cnt) ? keys[tid] : 0ull;
  for (int k = 2; k <= 64; k <<= 1) {
    for (int j = k >> 1; j >= 1; j >>= 1) {
      unsigned long long o = __shfl_xor((long long)v, j, 64);
      bool keepmax = (((tid & k) == 0) == ((tid & j) == 0));
      v = keepmax ? maxu64(v, o) : minu64(v, o);
    }
  }
  for (int k = 128; k <= CAP; k <<= 1) {
    for (int j = k >> 1; j >= 64; j >>= 1) {
      keys[tid] = v;
      __syncthreads();
      unsigned long long o = keys[tid ^ j];
      bool keepmax = (((tid & k) == 0) == ((tid & j) == 0));
      v = keepmax ? maxu64(v, o) : minu64(v, o);
      __syncthreads();
    }
    for (int j = 32; j >= 1; j >>= 1) {
      unsigned long long o = __shfl_xor((long long)v, j, 64);
      bool keepmax = (((tid & k) == 0) == ((tid & j) == 0));
      v = keepmax ? maxu64(v, o) : minu64(v, o);
    }
  }
  keys[tid] = v;
  __syncthreads();

  // phase 5: prefetch candidate boxes into LDS + cache areas (reference op
  // order (x2-x1)*(y2-y1); value identical to per-pair recomputation)
  if (v != 0ull) {
    unsigned int idx = ~(unsigned int)(v & 0xFFFFFFFFull);
    float4 cb = boxes[base + idx];
    cbox[tid] = cb;
    carea[tid] = (cb.z - cb.x) * (cb.w - cb.y);
  }
  __syncthreads();

  // phase 6: tiled parallel greedy NMS — identical result to the sequential
  // greedy scan (candidate c suppressed iff some SELECTED c' < c overlaps).
  // Per 256-candidate tile:
  //   A) parallel: byte flags "suppressed by a prior-tile selection"
  //   B) parallel: within-tile 256x256 overlap bit matrix
  //   C) wave-0 resolve via alive-mask: cost ~ #selections, not #candidates.
  //      Invariant: the minimum alive index can only be suppressed by a
  //      selected lower index, all already applied -> ctz order == greedy.
  for (int t = 0; t < 4; ++t) {
    int lo = t * 256;
    if (lo >= cnt) break;
    int tlen = cnt - lo; if (tlen > 256) tlen = 256;
    int nprior = s_nsel;
    if (nprior >= TOPK) break;

    // A: prior-selection suppression flags
    {
      int c = tid & 255;
      int s0 = tid >> 8;
      bool sup = false;
      if (c < tlen && nprior > 0) {
        float4 cb = cbox[lo + c];
        float ca = carea[lo + c];
        for (int s = s0; s < nprior; s += 4)
          sup |= iou_chk(selb[s * 5 + 0], selb[s * 5 + 1],
                         selb[s * 5 + 2], selb[s * 5 + 3], selarea[s],
                         cb.x, cb.y, cb.z, cb.w, ca);
      }
      psup4[s0][c] = sup ? (unsigned char)1 : (unsigned char)0;
    }

    // B: within-tile bit matrix (row j, word w: bits i = w*64+l, i < j)
    {
      int w = tid >> 8;          // 0..3
      int j = tid & 255;
      unsigned long long bits = 0ull;
      if (j < tlen) {
        float4 bj = cbox[lo + j];
        float aj = carea[lo + j];
        int ibeg = w * 64;
        int iend = ibeg + 64; if (iend > j) iend = j;
        for (int i = ibeg; i < iend; ++i) {
          float4 bi = cbox[lo + i];   // same addr across wave -> broadcast
          float ai = carea[lo + i];
          if (iou_chk(bi.x, bi.y, bi.z, bi.w, ai, bj.x, bj.y, bj.z, bj.w, aj))
            bits |= 1ull << (i & 63);
        }
      }
      tmat[j * 4 + w] = bits;
    }
    __syncthreads();

    // C: resolve on wave 0 (alive-mask greedy; ~10 ops per SELECTION)
    if (tid < 64) {
      int lane = tid;
      unsigned long long m0 = 0ull, m1 = 0ull, m2 = 0ull, m3 = 0ull;
      int nsel = nprior;

#define RESOLVE_SLOT(SLOT, MWORD)                                              \
      if ((SLOT) * 64 < tlen && nsel < TOPK) {                                 \
        const int cbase = (SLOT) * 64;                                         \
        unsigned long long ra = tmat[(cbase + lane) * 4 + 0];                  \
        unsigned long long rb = tmat[(cbase + lane) * 4 + 1];                  \
        unsigned long long rc = tmat[(cbase + lane) * 4 + 2];                  \
        unsigned long long rd = tmat[(cbase + lane) * 4 + 3];                  \
        unsigned long long rs =                                                \
            (SLOT) == 0 ? ra : ((SLOT) == 1 ? rb : ((SLOT) == 2 ? rc : rd));   \
        bool mypsup = (psup4[0][cbase + lane] | psup4[1][cbase + lane] |       \
                       psup4[2][cbase + lane] | psup4[3][cbase + lane]) != 0;  \
        int cend = tlen - cbase; if (cend > 64) cend = 64;                     \
        bool dead = mypsup |                                                   \
            (((ra & m0) | (rb & m1) | (rc & m2) | (rd & m3)) != 0ull);         \
        unsigned long long alive = __ballot(dead ? 0 : 1);                     \
        if (cend < 64) alive &= (1ull << cend) - 1ull;                         \
        while (alive != 0ull && nsel < TOPK) {                                 \
          int c = __ffsll((unsigned long long)alive) - 1;                      \
          MWORD |= 1ull << c;                                                  \
          if (lane == c) {                                                     \
            int gc = lo + cbase + c;                                           \
            float4 bx = cbox[gc];                                              \
            unsigned long long key = keys[gc];                                 \
            selb[nsel * 5 + 0] = bx.x; selb[nsel * 5 + 1] = bx.y;              \
            selb[nsel * 5 + 2] = bx.z; selb[nsel * 5 + 3] = bx.w;              \
            selarea[nsel]   = carea[gc];                                       \
            sel_idx[nsel]   = ~(unsigned int)(key & 0xFFFFFFFFull);            \
            sel_score[nsel] = __uint_as_float((unsigned int)(key >> 32));      \
          }                                                                    \
          nsel++;                                                              \
          bool killed = ((rs >> c) & 1ull) != 0ull;                            \
          alive &= ~__ballot(killed ? 1 : 0);                                  \
          alive &= ~(1ull << c);                                               \
        }                                                                      \
      }

      RESOLVE_SLOT(0, m0)
      RESOLVE_SLOT(1, m1)
      RESOLVE_SLOT(2, m2)
      RESOLVE_SLOT(3, m3)
#undef RESOLVE_SLOT

      if (lane == 0) s_nsel = nsel;
    }
    __syncthreads();
  }

  // phase 7: output rows [class_id, conf, xmin, ymin, xmax, ymax]
  int nsel = s_nsel;
  for (int e = tid; e < TOPK * 6; e += 1024) {
    int r = e / 6, col = e % 6;
    float val = 0.0f;
    if (r < nsel) {
      if (col == 0)      val = cls[base + sel_idx[r]];
      else if (col == 1) val = sel_score[r];
      else               val = selb[r * 5 + (col - 2)];
    }
    out[(size_t)b * (TOPK * 6) + e] = val;
  }
}

// ---------------------------------------------------------------- launch ----
extern "C" void kernel_launch(void* const* d_in, const int* in_sizes, int n_in,
                              void* d_out, int out_size, void* d_ws, size_t ws_size,
                              hipStream_t stream) {
  const float* yp = (const float*)d_in[0];
  float* out = (float*)d_out;
  char* ws = (char*)d_ws;

  const int total_anch = NANCH * NBATCH;              // 786048
  float4* boxes = (float4*)ws;
  float* scores = (float*)(ws + (size_t)total_anch * 16);
  float* cls    = (float*)(ws + (size_t)total_anch * 16 + (size_t)total_anch * 4);

  const int nblk = total_anch / APB;                  // 12282, exact
  decode_kernel<<<nblk, 256, 0, stream>>>(yp, boxes, scores, cls);
  nms_kernel<<<NBATCH, 1024, 0, stream>>>(boxes, scores, cls, out);
}

// Round 5
// 436.100 us; speedup vs baseline: 1.1798x; 1.0094x over previous
//
#include <hip/hip_runtime.h>
#include <stdint.h>

#define NANCH 24564
#define NBATCH 32
#define NCLS 81
#define FEAT 93
#define NEGV -10000000000.0f
#define CONF_T 0.01f
#define IOU_T 0.45f
#define TOPK 200
#define CAP 1024
#define TARGET 768u
#define NBINS 1024
#define APB 64   // anchors per decode block
#define NF4 (APB * FEAT / 4)   // 1488 float4 per block

// ---------------------------------------------------------------- decode ----
// 256 threads, 64 anchors/block. Staging via global_load_lds (direct DMA,
// no VGPR round-trip). Then 4 lanes per anchor for the 81-class argmax,
// merged via __shfl_xor with the first-index tie rule (matches jnp.argmax).
// Box decode is DEFERRED to the nms kernel (only ~4% of boxes are ever
// read); decode writes scores + cls only.
__global__ __launch_bounds__(256) void decode_kernel(
    const float* __restrict__ yp,
    float* __restrict__ scores, float* __restrict__ cls) {
#pragma clang fp contract(off)
  __shared__ float lds[APB * FEAT];   // 23808 B
  const float* src = yp + (size_t)blockIdx.x * (APB * FEAT);

  // global->LDS DMA: element i lands at LDS byte i*16; HW dest is
  // wave-uniform base (i&~63)*16 + lane*16, and i - (i&~63) == lane. exact.
  for (int i = threadIdx.x; i < NF4; i += 256) {
    int wb = i & ~63;   // wave-uniform
    __builtin_amdgcn_global_load_lds(
        (const __attribute__((address_space(1))) void*)(src + (size_t)i * 4),
        (__attribute__((address_space(3))) void*)(lds + wb * 4),
        16, 0, 0);
  }
  __syncthreads();   // compiler drains vmcnt before s_barrier

  const int L = threadIdx.x;
  const int a = L >> 2;          // anchor within block
  const int part = L & 3;
  const float* p = &lds[a * FEAT];

  int c0 = part * 21;
  int c1 = (part == 3) ? NCLS : c0 + 21;
  float best = -3.0e38f;
  int bi = c0;
  for (int c = c0; c < c1; ++c) {  // strict > keeps first index within part
    float v = p[c];
    if (v > best) { best = v; bi = c; }
  }
  // merge 4 parts: smaller index wins ties (parts are index-ordered)
  for (int off = 1; off < 4; off <<= 1) {
    float ov = __shfl_xor(best, off, 64);
    int   oi = __shfl_xor(bi, off, 64);
    if (ov > best || (ov == best && oi < bi)) { best = ov; bi = oi; }
  }

  if (part == 0) {
    int ga = blockIdx.x * APB + a;
    cls[ga] = (float)bi;
    scores[ga] = (bi != 0 && best > CONF_T) ? best : NEGV;
  }
}

// Exact division-free IoU threshold test (bit-exact vs reference; verified
// absmax 0.0 in rounds 1, 3, 4). RN_f32(inter/uni) > 0.45f <=> inter/uni > M
// where M = midpoint(0.45f, nextafter(0.45f,+inf)); tie-to-even at M rounds
// to 0.45f (even mantissa) so the boundary is strict. M has 25 mantissa
// bits, uni has <=24 -> M*uni is EXACT in f64, so the f64 compare is
// bit-equivalent to the reference's f32 divide-and-compare. Areas are
// cached (computed once with the reference op order), value-identical.
__device__ __forceinline__ bool iou_chk(float sx1, float sy1, float sx2, float sy2, float sarea,
                                        float bx1, float by1, float bx2, float by2, float barea) {
#pragma clang fp contract(off)
  float ix1 = fmaxf(sx1, bx1);
  float iy1 = fmaxf(sy1, by1);
  float ix2 = fminf(sx2, bx2);
  float iy2 = fminf(sy2, by2);
  float inter = fmaxf(ix2 - ix1, 0.0f) * fmaxf(iy2 - iy1, 0.0f);
  float uni = sarea + barea - inter;   // same f32 value as reference
  const double UMID = 0.5 * ((double)0.45f + (double)__uint_as_float(0x3EE66667u));
  return (uni > 0.0f) & ((double)inter > UMID * (double)uni);
}

__device__ __forceinline__ unsigned long long maxu64(unsigned long long a, unsigned long long b) { return a > b ? a : b; }
__device__ __forceinline__ unsigned long long minu64(unsigned long long a, unsigned long long b) { return a < b ? a : b; }

// ------------------------------------------------------------------- nms ----
__global__ __launch_bounds__(1024) void nms_kernel(
    const float* __restrict__ yp, const float* __restrict__ scores,
    const float* __restrict__ cls, float* __restrict__ out) {
#pragma clang fp contract(off)
  __shared__ unsigned long long keys[CAP];   // 8 KB
  __shared__ float4 cbox[CAP];               // 16 KB
  __shared__ float carea[CAP];               // 4 KB candidate areas
  __shared__ unsigned int hist[NBINS];       // 4 KB
  __shared__ unsigned long long tmat[256 * 4];  // 8 KB within-tile bit matrix
  __shared__ unsigned char psup4[4][256];    // 1 KB prior-selection suppression
  __shared__ float selb[TOPK * 5];
  __shared__ float selarea[TOPK];
  __shared__ unsigned int sel_idx[TOPK];
  __shared__ float sel_score[TOPK];
  __shared__ unsigned int s_cnt;
  __shared__ int s_cutoff;
  __shared__ int s_nsel;

  const int b = blockIdx.x;
  const int tid = threadIdx.x;
  const size_t base = (size_t)b * NANCH;

  // phase 0: load 24 scores into registers (single global pass)
  float sreg[24];
#pragma unroll
  for (int j = 0; j < 24; ++j) {
    int i = tid + j * 1024;
    sreg[j] = (i < NANCH) ? scores[base + i] : NEGV;
  }

  // phase 1: histogram
  hist[tid] = 0u;
  if (tid == 0) { s_cnt = 0u; s_cutoff = 0; s_nsel = 0; }
  __syncthreads();
#pragma unroll
  for (int j = 0; j < 24; ++j) {
    float s = sreg[j];
    if (s >= 0.0f) {
      int bin = (int)(s * ((float)NBINS / 6.0f));
      bin = bin > (NBINS - 1) ? (NBINS - 1) : bin;
      atomicAdd(&hist[bin], 1u);
    }
  }
  __syncthreads();

  // phase 2: suffix-inclusive sums over 1024 bins, wave 0 only (shuffle scan)
  if (tid < 64) {
    int lane = tid;
    unsigned int h[16];
    unsigned int S = 0;
#pragma unroll
    for (int t = 0; t < 16; ++t) { h[t] = hist[lane * 16 + t]; S += h[t]; }
    unsigned int incl = S;
    for (int off = 1; off < 64; off <<= 1) {
      unsigned int o = __shfl_down(incl, off, 64);
      if (lane + off < 64) incl += o;
    }
    unsigned int acc = incl - S;   // exclusive suffix
#pragma unroll
    for (int t = 15; t >= 0; --t) { acc += h[t]; hist[lane * 16 + t] = acc; }
  }
  __syncthreads();
  {
    unsigned int sfx = hist[tid];
    unsigned int nxt = (tid < NBINS - 1) ? hist[tid + 1] : 0u;
    if (sfx >= TARGET && nxt < TARGET) s_cutoff = tid;   // unique writer
  }
  __syncthreads();
  float cutoffv = (float)s_cutoff * (6.0f / (float)NBINS);

  // phase 3: compact candidates >= cutoff from registers
#pragma unroll
  for (int j = 0; j < 24; ++j) {
    float s = sreg[j];
    if (s >= cutoffv) {   // NEGV always excluded
      unsigned int pos = atomicAdd(&s_cnt, 1u);
      if (pos < CAP) {
        unsigned int i = (unsigned int)(tid + j * 1024);
        keys[pos] = ((unsigned long long)__float_as_uint(s) << 32) |
                    (unsigned long long)(~i);
      }
    }
  }
  __syncthreads();
  int cnt = (int)(s_cnt > CAP ? CAP : s_cnt);

  // phase 4: hybrid bitonic sort (descending), 1 elem/thread.
  // j<64 steps: wave-local via 64-bit shfl_xor (no barrier). j>=64: LDS.
  unsigned long long v = (tid < cnt) ? keys[tid] : 0ull;
  for (int k = 2; k <= 64; k <<= 1) {
    for (int j = k >> 1; j >= 1; j >>= 1) {
      unsigned long long o = __shfl_xor((long long)v, j, 64);
      bool keepmax = (((tid & k) == 0) == ((tid & j) == 0));
      v = keepmax ? maxu64(v, o) : minu64(v, o);
    }
  }
  for (int k = 128; k <= CAP; k <<= 1) {
    for (int j = k >> 1; j >= 64; j >>= 1) {
      keys[tid] = v;
      __syncthreads();
      unsigned long long o = keys[tid ^ j];
      bool keepmax = (((tid & k) == 0) == ((tid & j) == 0));
      v = keepmax ? maxu64(v, o) : minu64(v, o);
      __syncthreads();
    }
    for (int j = 32; j >= 1; j >>= 1) {
      unsigned long long o = __shfl_xor((long long)v, j, 64);
      bool keepmax = (((tid & k) == 0) == ((tid & j) == 0));
      v = keepmax ? maxu64(v, o) : minu64(v, o);
    }
  }
  keys[tid] = v;
  __syncthreads();

  // phase 5: decode candidate boxes directly from y_pred (deferred decode;
  // identical expression text + fp contract off + same expf -> bit-identical
  // to the old decode-kernel path) and cache areas (reference op order).
  if (v != 0ull) {
    unsigned int idx = ~(unsigned int)(v & 0xFFFFFFFFull);
    const float* p = yp + (base + (size_t)idx) * FEAT;
    float cx = p[81] * p[89] * p[87] + p[85];
    float cy = p[82] * p[90] * p[88] + p[86];
    float w  = expf(p[83] * p[91]) * p[87];
    float h  = expf(p[84] * p[92]) * p[88];
    float xmin = (cx - 0.5f * w) * 512.0f;
    float ymin = (cy - 0.5f * h) * 512.0f;
    float xmax = (cx + 0.5f * w) * 512.0f;
    float ymax = (cy + 0.5f * h) * 512.0f;
    float4 cb = make_float4(xmin, ymin, xmax, ymax);
    cbox[tid] = cb;
    carea[tid] = (cb.z - cb.x) * (cb.w - cb.y);
  }
  __syncthreads();

  // phase 6: tiled parallel greedy NMS — identical result to the sequential
  // greedy scan (candidate c suppressed iff some SELECTED c' < c overlaps).
  // Per 256-candidate tile:
  //   A) parallel: byte flags "suppressed by a prior-tile selection"
  //   B) parallel: within-tile 256x256 overlap bit matrix
  //   C) wave-0 resolve via alive-mask: cost ~ #selections, not #candidates.
  //      Invariant: the minimum alive index can only be suppressed by a
  //      selected lower index, all already applied -> ctz order == greedy.
  for (int t = 0; t < 4; ++t) {
    int lo = t * 256;
    if (lo >= cnt) break;
    int tlen = cnt - lo; if (tlen > 256) tlen = 256;
    int nprior = s_nsel;
    if (nprior >= TOPK) break;

    // A: prior-selection suppression flags
    {
      int c = tid & 255;
      int s0 = tid >> 8;
      bool sup = false;
      if (c < tlen && nprior > 0) {
        float4 cb = cbox[lo + c];
        float ca = carea[lo + c];
        for (int s = s0; s < nprior; s += 4)
          sup |= iou_chk(selb[s * 5 + 0], selb[s * 5 + 1],
                         selb[s * 5 + 2], selb[s * 5 + 3], selarea[s],
                         cb.x, cb.y, cb.z, cb.w, ca);
      }
      psup4[s0][c] = sup ? (unsigned char)1 : (unsigned char)0;
    }

    // B: within-tile bit matrix (row j, word w: bits i = w*64+l, i < j)
    {
      int w = tid >> 8;          // 0..3
      int j = tid & 255;
      unsigned long long bits = 0ull;
      if (j < tlen) {
        float4 bj = cbox[lo + j];
        float aj = carea[lo + j];
        int ibeg = w * 64;
        int iend = ibeg + 64; if (iend > j) iend = j;
        for (int i = ibeg; i < iend; ++i) {
          float4 bi = cbox[lo + i];   // same addr across wave -> broadcast
          float ai = carea[lo + i];
          if (iou_chk(bi.x, bi.y, bi.z, bi.w, ai, bj.x, bj.y, bj.z, bj.w, aj))
            bits |= 1ull << (i & 63);
        }
      }
      tmat[j * 4 + w] = bits;
    }
    __syncthreads();

    // C: resolve on wave 0 (alive-mask greedy; ~10 ops per SELECTION)
    if (tid < 64) {
      int lane = tid;
      unsigned long long m0 = 0ull, m1 = 0ull, m2 = 0ull, m3 = 0ull;
      int nsel = nprior;

#define RESOLVE_SLOT(SLOT, MWORD)                                              \
      if ((SLOT) * 64 < tlen && nsel < TOPK) {                                 \
        const int cbase = (SLOT) * 64;                                         \
        unsigned long long ra = tmat[(cbase + lane) * 4 + 0];                  \
        unsigned long long rb = tmat[(cbase + lane) * 4 + 1];                  \
        unsigned long long rc = tmat[(cbase + lane) * 4 + 2];                  \
        unsigned long long rd = tmat[(cbase + lane) * 4 + 3];                  \
        unsigned long long rs =                                                \
            (SLOT) == 0 ? ra : ((SLOT) == 1 ? rb : ((SLOT) == 2 ? rc : rd));   \
        bool mypsup = (psup4[0][cbase + lane] | psup4[1][cbase + lane] |       \
                       psup4[2][cbase + lane] | psup4[3][cbase + lane]) != 0;  \
        int cend = tlen - cbase; if (cend > 64) cend = 64;                     \
        bool dead = mypsup |                                                   \
            (((ra & m0) | (rb & m1) | (rc & m2) | (rd & m3)) != 0ull);         \
        unsigned long long alive = __ballot(dead ? 0 : 1);                     \
        if (cend < 64) alive &= (1ull << cend) - 1ull;                         \
        while (alive != 0ull && nsel < TOPK) {                                 \
          int c = __ffsll((unsigned long long)alive) - 1;                      \
          MWORD |= 1ull << c;                                                  \
          if (lane == c) {                                                     \
            int gc = lo + cbase + c;                                           \
            float4 bx = cbox[gc];                                              \
            unsigned long long key = keys[gc];                                 \
            selb[nsel * 5 + 0] = bx.x; selb[nsel * 5 + 1] = bx.y;              \
            selb[nsel * 5 + 2] = bx.z; selb[nsel * 5 + 3] = bx.w;              \
            selarea[nsel]   = carea[gc];                                       \
            sel_idx[nsel]   = ~(unsigned int)(key & 0xFFFFFFFFull);            \
            sel_score[nsel] = __uint_as_float((unsigned int)(key >> 32));      \
          }                                                                    \
          nsel++;                                                              \
          bool killed = ((rs >> c) & 1ull) != 0ull;                            \
          alive &= ~__ballot(killed ? 1 : 0);                                  \
          alive &= ~(1ull << c);                                               \
        }                                                                      \
      }

      RESOLVE_SLOT(0, m0)
      RESOLVE_SLOT(1, m1)
      RESOLVE_SLOT(2, m2)
      RESOLVE_SLOT(3, m3)
#undef RESOLVE_SLOT

      if (lane == 0) s_nsel = nsel;
    }
    __syncthreads();
  }

  // phase 7: output rows [class_id, conf, xmin, ymin, xmax, ymax]
  int nsel = s_nsel;
  for (int e = tid; e < TOPK * 6; e += 1024) {
    int r = e / 6, col = e % 6;
    float val = 0.0f;
    if (r < nsel) {
      if (col == 0)      val = cls[base + sel_idx[r]];
      else if (col == 1) val = sel_score[r];
      else               val = selb[r * 5 + (col - 2)];
    }
    out[(size_t)b * (TOPK * 6) + e] = val;
  }
}

// ---------------------------------------------------------------- launch ----
extern "C" void kernel_launch(void* const* d_in, const int* in_sizes, int n_in,
                              void* d_out, int out_size, void* d_ws, size_t ws_size,
                              hipStream_t stream) {
  const float* yp = (const float*)d_in[0];
  float* out = (float*)d_out;
  char* ws = (char*)d_ws;

  const int total_anch = NANCH * NBATCH;              // 786048
  float* scores = (float*)ws;
  float* cls    = (float*)(ws + (size_t)total_anch * 4);

  const int nblk = total_anch / APB;                  // 12282, exact
  decode_kernel<<<nblk, 256, 0, stream>>>(yp, scores, cls);
  nms_kernel<<<NBATCH, 1024, 0, stream>>>(yp, scores, cls, out);
}